// Round 1
// baseline (273.330 us; speedup 1.0000x reference)
//
#include <hip/hip_runtime.h>

// Problem constants (from reference):
//   N = 64 (protein length), B = 32 (batch), L = 2N-1 = 127 (lattice side)
//   out = (B, L, L, L) float32 = 65,548,256 elems = 262,193,024 B (~262 MB)
//
// R2 theory: the ~160us fillBufferAligned dispatches in the profile are the
// HARNESS's re-poison fills (1.049 GB @ 6.5 TB/s) and sit inside the timed
// window — an invariant floor. Our controllable slice is zero(~80us) +
// scatter(~3us). The old zero kernel (64,013 one-shot blocks, 1 store/thread)
// ran at ~3.3 TB/s; the rocclr fill proves 6.5 TB/s is reachable with
// persistent grid-stride blocks and deep fire-and-forget stores.
// Fix: 4096 persistent blocks (16/CU), grid-stride nontemporal float4 stores.

constexpr int PN = 64;
constexpr int PB = 32;
constexpr int PL = 2 * PN - 1;  // 127
constexpr long long TOTAL_F = (long long)PB * PL * PL * PL;   // 65,548,256 (divisible by 4)
constexpr long long TOTAL_V4 = TOTAL_F / 4;                   // 16,387,064 float4s

// clang's __builtin_nontemporal_store needs a real vector type, not HIP's
// float4 struct.
typedef float v4f __attribute__((ext_vector_type(4)));

constexpr int ZB = 256;     // block size (multiple of 64)
constexpr int ZGRID = 4096; // persistent blocks: 16 per CU on 256 CUs
                            // -> each thread stores ~15.6 float4s grid-stride

__global__ __launch_bounds__(ZB) void lattice_zero_kernel(v4f* __restrict__ out) {
    const v4f z = {0.f, 0.f, 0.f, 0.f};
    const long long stride = (long long)ZGRID * ZB;
    long long t = (long long)blockIdx.x * ZB + threadIdx.x;
    // Coalesced grid-stride: consecutive lanes hit consecutive 16B segments;
    // stores are fire-and-forget (no dependent loads), nt hint skips L2
    // allocation for a 262MB stream that can't fit the 32MB L2 anyway.
    for (; t < TOTAL_V4; t += stride) {
        __builtin_nontemporal_store(z, out + t);
    }
}

__global__ void lattice_scatter_kernel(const float* __restrict__ acids,
                                       const int*   __restrict__ idx,
                                       const int*   __restrict__ mask,
                                       float*       __restrict__ out) {
    int t = blockIdx.x * blockDim.x + threadIdx.x;   // 0 .. B*N-1
    if (t >= PB * PN) return;
    if (mask[t] == 0) return;        // masked-off acids scatter 0 -> no-op under add
    float v = acids[t];
    int b = t >> 6;                  // t / N  (N == 64)
    int i0 = idx[3 * t + 0] + (PN - 1);
    int i1 = idx[3 * t + 1] + (PN - 1);
    int i2 = idx[3 * t + 2] + (PN - 1);
    size_t off = ((((size_t)b * PL + i0) * PL) + i1) * PL + i2;
    atomicAdd(out + off, v);         // device-scope; handles index collisions
}

extern "C" void kernel_launch(void* const* d_in, const int* in_sizes, int n_in,
                              void* d_out, int out_size, void* d_ws, size_t ws_size,
                              hipStream_t stream) {
    const float* acids = (const float*)d_in[0];   // (B,N) f32
    const int*   idx   = (const int*)  d_in[1];   // (B,N,3) i32
    const int*   mask  = (const int*)  d_in[2];   // (B,N) bool -> i32 per harness
    float* out = (float*)d_out;

    // Zero the lattice with persistent grid-stride blocks at the write-only
    // HBM ceiling.
    lattice_zero_kernel<<<ZGRID, ZB, 0, stream>>>((v4f*)out);

    // Scatter-add the <=2048 masked values (stream-ordered after the zero).
    constexpr int total = PB * PN;   // 2048
    lattice_scatter_kernel<<<(total + 255) / 256, 256, 0, stream>>>(acids, idx, mask, out);
}

// Round 2
// 223.597 us; speedup vs baseline: 1.2224x; 1.2224x over previous
//
#include <hip/hip_runtime.h>

// Problem constants (from reference):
//   N = 64 (protein length), B = 32 (batch), L = 2N-1 = 127 (lattice side)
//   out = (B, L, L, L) float32 = 65,548,256 elems = 262,193,024 B (~262 MB)
//
// R2 post-mortem: nontemporal grid-stride zero REGRESSED (our slice 85->103us).
// nt bypasses L2 write-combining -> partial-line HBM writes. Reverted.
//
// R2 key insight: the ~160us fillBufferAligned dispatches write 1.049 GB
// (= 4x output, the harness's guard-padded poison) at 6.3-6.5 TB/s. That
// proves the rocclr fill path IS a ~6.5 TB/s writer on this chip. The old
// session's "hipMemsetAsync = 1.7 TB/s" claim matches exactly what you get
// if you misattribute the poison fill's 160us to a 262MB fill -> it was a
// misattribution. So: use hipMemsetAsync (stream-ordered, graph-capturable,
// same path as the proven fill) for the zero, custom kernel only for the
// 2048-point scatter-add.
//
// Expected floor: poison ~163us (harness-owned, untouchable) + zero ~44us
// (262MB @ ~6 TB/s) + scatter ~3us + gaps => ~210us total.

constexpr int PN = 64;
constexpr int PB = 32;
constexpr int PL = 2 * PN - 1;  // 127

__global__ void lattice_scatter_kernel(const float* __restrict__ acids,
                                       const int*   __restrict__ idx,
                                       const int*   __restrict__ mask,
                                       float*       __restrict__ out) {
    int t = blockIdx.x * blockDim.x + threadIdx.x;   // 0 .. B*N-1
    if (t >= PB * PN) return;
    if (mask[t] == 0) return;        // masked-off acids scatter 0 -> no-op under add
    float v = acids[t];
    int b = t >> 6;                  // t / N  (N == 64)
    int i0 = idx[3 * t + 0] + (PN - 1);
    int i1 = idx[3 * t + 1] + (PN - 1);
    int i2 = idx[3 * t + 2] + (PN - 1);
    size_t off = ((((size_t)b * PL + i0) * PL) + i1) * PL + i2;
    atomicAdd(out + off, v);         // device-scope; handles index collisions
}

extern "C" void kernel_launch(void* const* d_in, const int* in_sizes, int n_in,
                              void* d_out, int out_size, void* d_ws, size_t ws_size,
                              hipStream_t stream) {
    const float* acids = (const float*)d_in[0];   // (B,N) f32
    const int*   idx   = (const int*)  d_in[1];   // (B,N,3) i32
    const int*   mask  = (const int*)  d_in[2];   // (B,N) bool -> i32 per harness
    float* out = (float*)d_out;

    // Zero the lattice via the rocclr fill path (demonstrated 6.3-6.5 TB/s on
    // the 1.049GB poison fill of this very buffer). Stream-ordered and
    // graph-capturable.
    hipMemsetAsync(out, 0, (size_t)out_size, stream);

    // Scatter-add the <=2048 masked values (stream-ordered after the zero).
    constexpr int total = PB * PN;   // 2048
    lattice_scatter_kernel<<<(total + 255) / 256, 256, 0, stream>>>(acids, idx, mask, out);
}